// Round 12
// baseline (4547.500 us; speedup 1.0000x reference)
//
#include <hip/hip_runtime.h>
#include <math.h>

#define FF 128     // feature width (all layers)
#define G0F 1024   // gemm0 blocks inside fused2 (4/CU tail)
#define PB 1024    // persistent blocks for agg_gemm_pipe

typedef _Float16 half2v __attribute__((ext_vector_type(2)));
typedef _Float16 f16x8  __attribute__((ext_vector_type(8)));
typedef __fp16   fp16x2 __attribute__((ext_vector_type(2)));
typedef __attribute__((ext_vector_type(4))) float f4v;

__device__ __forceinline__ half2v u2h(unsigned u) {
    union { unsigned u; half2v h; } c; c.u = u; return c.h;
}
__device__ __forceinline__ unsigned h2u(half2v h) {
    union { unsigned u; half2v h; } c; c.h = h; return c.u;
}
__device__ __forceinline__ unsigned short f2h(float f) {
    _Float16 h = (_Float16)f;
    unsigned short u; __builtin_memcpy(&u, &h, 2); return u;
}
__device__ __forceinline__ half2v pk2h(float e) {
    union { fp16x2 p; half2v h; } c;
    c.p = __builtin_amdgcn_cvt_pkrtz(e, e);
    return c.h;
}
__device__ __forceinline__ float dot2(half2v a, half2v b, float c) {
#if __has_builtin(__builtin_amdgcn_fdot2)
    union { half2v h; fp16x2 p; } ca, cb;
    ca.h = a; cb.h = b;
    return __builtin_amdgcn_fdot2(ca.p, cb.p, c, false);
#else
    return c + (float)a.x * (float)b.x + (float)a.y * (float)b.y;
#endif
}
__device__ __forceinline__ half2v shfladd_h(half2v v, int mask) {
    return v + u2h(__shfl_xor(h2u(v), mask));
}
// 16B-chunk XOR swizzle inside a [16 rows][256B] LDS tile.
__device__ __forceinline__ int swz16(int row, int chunk) {
    return row * 256 + (((chunk ^ row) & 15) << 4);
}

// =====================================================================
// R25: agg_gemm_pipe -- persistent-block work queue overlapping
// aggregate(l) with gemm(l+1). R23's intra-block fusion serialized the
// two phases (105us = 67+38); here producer items (4 nodes each) and
// consumer items (16-row gemm tile, needs ONLY its own 4 producers)
// are interleaved in the item stream [4 agg, 1 gemm]*3125 and claimed
// dynamically by 1024 persistent blocks -- gemm tiles run on other
// blocks throughout the aggregate, not after it. Ready-flags: producer
// release-add per tile; consumer tid0 acquire-spins to 4. Deadlock-free:
// counter order hands a tile's producers out strictly before the tile.
// Aggregate internals stay R19-exact (every variation R20-R23 lost).
// R24 counters: aggregate FETCH 126MB = compulsory set; L3 absorbs all
// gather re-reads -> internal operating point unmovable; overlap is
// the only remaining slack.
// =====================================================================

// ---------------- pack0: pack W0 + att (tiny pre-kernel) -------------
__global__ __launch_bounds__(256) void pack0(
    const float* __restrict__ W0s_, const float* __restrict__ W0d_,
    unsigned short* __restrict__ Wp,
    const float* __restrict__ a0, const float* __restrict__ a1,
    const float* __restrict__ a2, unsigned* __restrict__ attH)
{
    int b = blockIdx.x;
    const int tid = threadIdx.x;
    if (b < 512) {                       // 4r x 2mat x 128 x 128 = 131072
        const int t = b * 256 + tid;
        const int r   = t >> 15;
        const int mat = (t >> 14) & 1;
        const int idx = t & 16383;
        const int k = idx >> 7, nn = idx & 127;
        const float* W = mat ? W0d_ : W0s_;
        const float v = W[((size_t)r * FF + k) * FF + nn];
        const int nb = nn >> 4, lo = nn & 15;
        const int ks = k >> 5, quad = (k >> 3) & 3, j = k & 7;
        const int lane = quad * 16 + lo;
        const size_t o = ((((((size_t)r * 2 + mat) * 8 + nb) * 4 + ks) * 64 + lane) * 8) + j;
        Wp[o] = f2h(v);
        return;
    }
    b -= 512;
    const int t = b * 256 + tid;
    if (t >= 768) return;
    const int l = t >> 8, rest = t & 255;
    const float* a = (l == 0) ? a0 : (l == 1) ? a1 : a2;
    const float2 v = ((const float2*)a)[rest];
    half2v h = {(_Float16)v.x, (_Float16)v.y};
    attH[t] = h2u(h);
}

// ------- fused2: csr fill (record) + gemm0 + pack W1/W2 --------------
__global__ __launch_bounds__(256, 4) void fused2(
    const int* __restrict__ esrc_all, const int* __restrict__ edst_all,
    int* __restrict__ rec, int* __restrict__ ovf,
    int totalE, int ne, int n, int CB,
    const float* __restrict__ x,
    const unsigned short* __restrict__ Wp,
    const float* __restrict__ bs0, const float* __restrict__ bd0,
    unsigned short* __restrict__ fs_all, unsigned short* __restrict__ fd_all,
    int nrb,
    const float* __restrict__ W1s_, const float* __restrict__ W1d_,
    const float* __restrict__ W2s_, const float* __restrict__ W2d_,
    unsigned short* __restrict__ Wp_full)
{
    __shared__ char lsA[4096];
    __shared__ char lsC[8192];

    int b = blockIdx.x;
    const int tid = threadIdx.x;
    const int L = n << 2;

    if (b < CB) {
        // ---- padded-CSR fill, record layout, 4 chains/thread ----
        const int t0 = b * 1024 + tid;
        #pragma unroll
        for (int k = 0; k < 4; ++k) {
            const int i = t0 + k * 256;
            if (i < totalE) {
                const int r = i / ne;
                const int rd = r * n + edst_all[i];
                const int src = esrc_all[i];
                const int idx = atomicAdd(&rec[(size_t)rd * 16], 1);
                if (idx < 15)      rec[(size_t)rd * 16 + 1 + idx] = src;
                else if (idx < 32) ovf[(size_t)(idx - 15) * L + rd] = src;
            }
        }
        return;
    }
    b -= CB;

    if (b < G0F) {
        // ---- layer-0 GEMM (f32 x, packed-Wp B), LDS-staged ----
        const int wave = tid >> 6, lane = tid & 63;
        const int r = b & 3;
        const int half = wave & 1;
        const int mat  = wave >> 1;
        const int lo = lane & 15, quad = lane >> 4;

        const unsigned short* Wr = Wp + (size_t)r * 2 * FF * FF;
        const float* bp = mat ? bd0 : bs0;
        unsigned short* fs = fs_all + (size_t)r * n * FF;
        unsigned short* fd = fd_all + (size_t)r * n * FF;

        f16x8 B[4][4];
        #pragma unroll
        for (int nbi = 0; nbi < 4; ++nbi)
            #pragma unroll
            for (int ks = 0; ks < 4; ++ks) {
                const int nb = half * 4 + nbi;
                B[nbi][ks] = *(const f16x8*)
                    &Wr[(((((size_t)mat * 8 + nb) * 4 + ks) * 64 + lane) * 8)];
            }

        float bias[4];
        #pragma unroll
        for (int nbi = 0; nbi < 4; ++nbi)
            bias[nbi] = bp[r * FF + (half * 4 + nbi) * 16 + lo];

        const int srow = tid >> 4, schunk = tid & 15;
        const int stride = G0F >> 2;
        for (int rb = b >> 2; rb < nrb; rb += stride) {
            const int row0 = rb * 16;
            {
                const float* xs = &x[(size_t)row0 * FF + tid * 8];
                const float4 p0 = *(const float4*)&xs[0];
                const float4 p1 = *(const float4*)&xs[4];
                f16x8 v;
                v[0] = (_Float16)p0.x; v[1] = (_Float16)p0.y;
                v[2] = (_Float16)p0.z; v[3] = (_Float16)p0.w;
                v[4] = (_Float16)p1.x; v[5] = (_Float16)p1.y;
                v[6] = (_Float16)p1.z; v[7] = (_Float16)p1.w;
                *(f16x8*)&lsA[swz16(srow, schunk)] = v;
            }
            __syncthreads();

            f16x8 A[4];
            #pragma unroll
            for (int ks = 0; ks < 4; ++ks)
                A[ks] = *(const f16x8*)&lsA[swz16(lo, ks * 4 + quad)];

            f4v c[4];
            #pragma unroll
            for (int nbi = 0; nbi < 4; ++nbi)
                c[nbi] = (f4v){bias[nbi], bias[nbi], bias[nbi], bias[nbi]};

            #pragma unroll
            for (int ks = 0; ks < 4; ++ks)
                #pragma unroll
                for (int nbi = 0; nbi < 4; ++nbi)
                    c[nbi] = __builtin_amdgcn_mfma_f32_16x16x32_f16(
                        A[ks], B[nbi][ks], c[nbi], 0, 0, 0);

            #pragma unroll
            for (int nbi = 0; nbi < 4; ++nbi)
                #pragma unroll
                for (int i = 0; i < 4; ++i) {
                    const int row = quad * 4 + i;
                    const int cb  = ((half * 4 + nbi) * 16 + lo) * 2;
                    *(unsigned short*)&lsC[mat * 4096 + swz16(row, cb >> 4) + (cb & 15)]
                        = f2h(c[nbi][i]);
                }
            __syncthreads();

            #pragma unroll
            for (int p = 0; p < 2; ++p) {
                const int unit = p * 256 + tid;
                const int m    = unit >> 8;
                const int row  = (unit >> 4) & 15;
                const int ch   = unit & 15;
                const uint4 d = *(const uint4*)&lsC[m * 4096 + swz16(row, ch)];
                unsigned short* out = m ? fd : fs;
                *(uint4*)&out[(size_t)(row0 + row) * FF + ch * 8] = d;
            }
            __syncthreads();
        }
        return;
    }
    b -= G0F;

    // ---- pack W for layers 1,2 ----
    const int t = b * 256 + tid;
    if (t >= 2 * 4 * 2 * FF * FF) return;
    const int l    = 1 + (t >> 17);
    const int rest = t & 131071;
    const int r    = rest >> 15;
    const int mat  = (rest >> 14) & 1;
    const int idx  = rest & 16383;
    const int k = idx >> 7, nn = idx & 127;
    const float* W = (l == 1) ? (mat ? W1d_ : W1s_)
                              : (mat ? W2d_ : W2s_);
    const float v = W[((size_t)r * FF + k) * FF + nn];
    const int nb = nn >> 4, lo = nn & 15;
    const int ks = k >> 5, quad = (k >> 3) & 3, j = k & 7;
    const int lane = quad * 16 + lo;
    const size_t o = (((((((size_t)l * 4 + r) * 2 + mat) * 8 + nb) * 4 + ks) * 64 + lane) * 8) + j;
    Wp_full[o] = f2h(v);
}

// =====================================================================
// Shared aggregate building block (R19 pair structure, per node).
// =====================================================================
__device__ __forceinline__ void edge4(
    uint4 g, bool ok, const half2v* fdv, const half2v* atv,
    float& den, half2v* acc)
{
    const half2v C02 = {(_Float16)0.2f, (_Float16)0.2f};
    half2v f[4] = {u2h(g.x), u2h(g.y), u2h(g.z), u2h(g.w)};
    float v = 0.f;
    #pragma unroll
    for (int i = 0; i < 4; ++i) {
        const half2v z = f[i] + fdv[i];
        const half2v l = __builtin_elementwise_max(z, z * C02);
        v = dot2(l, atv[i], v);
    }
    v += __shfl_xor(v, 2);
    v += __shfl_xor(v, 1);
    const float e = ok ? __expf(v) : 0.f;
    den += e;
    const half2v eh = pk2h(e);
    #pragma unroll
    for (int i = 0; i < 4; ++i) acc[i] += eh * f[i];
}

// Computes val[4] (packed f16 pairs) for one node; all 64 lanes.
__device__ __forceinline__ void agg_node(
    int node, int n, int quarter, int fo,
    const int* __restrict__ rec, const int* __restrict__ ovf,
    const unsigned* __restrict__ fs_all, const unsigned* __restrict__ fd_all,
    const unsigned* __restrict__ att_h, half2v* val)
{
    const int L = n << 2;
    int m[4], i0[4], i1[4];
    #pragma unroll
    for (int r = 0; r < 4; ++r) {
        const int rd = r * n + node;
        const int* rp = &rec[(size_t)rd * 16];
        m[r]  = rp[0];
        i0[r] = rp[1 + quarter];
        i1[r] = rp[5 + quarter];
    }

    #pragma unroll
    for (int i = 0; i < 4; ++i) val[i] = (half2v){(_Float16)0.f, (_Float16)0.f};

    #pragma unroll
    for (int rp2 = 0; rp2 < 2; ++rp2) {
        const int ra = 2 * rp2, rb = 2 * rp2 + 1;
        const int rdA = ra * n + node;
        const int rdB = rb * n + node;
        const int mA = m[ra], mB = m[rb];
        const unsigned* fsuA = fs_all + (size_t)ra * n * 64;
        const unsigned* fsuB = fs_all + (size_t)rb * n * 64;

        const uint4 ufdA = *(const uint4*)&fd_all[(size_t)rdA * 64 + fo];
        const uint4 ufdB = *(const uint4*)&fd_all[(size_t)rdB * 64 + fo];
        const uint4 uatA = *(const uint4*)&att_h[ra * 64 + fo];
        const uint4 uatB = *(const uint4*)&att_h[rb * 64 + fo];

        const bool okA0 = quarter < mA, okA1 = 4 + quarter < mA;
        const bool okB0 = quarter < mB, okB1 = 4 + quarter < mB;
        int iA0 = okA0 ? i0[ra] : 0;
        int iB0 = okB0 ? i0[rb] : 0;
        int iA1 = okA1 ? i1[ra] : 0;
        int iB1 = okB1 ? i1[rb] : 0;
        const uint4 gA0 = *(const uint4*)&fsuA[(size_t)iA0 * 64 + fo];
        const uint4 gB0 = *(const uint4*)&fsuB[(size_t)iB0 * 64 + fo];
        const uint4 gA1 = *(const uint4*)&fsuA[(size_t)iA1 * 64 + fo];
        const uint4 gB1 = *(const uint4*)&fsuB[(size_t)iB1 * 64 + fo];

        half2v fdvA[4] = {u2h(ufdA.x), u2h(ufdA.y), u2h(ufdA.z), u2h(ufdA.w)};
        half2v atvA[4] = {u2h(uatA.x), u2h(uatA.y), u2h(uatA.z), u2h(uatA.w)};
        half2v fdvB[4] = {u2h(ufdB.x), u2h(ufdB.y), u2h(ufdB.z), u2h(ufdB.w)};
        half2v atvB[4] = {u2h(uatB.x), u2h(uatB.y), u2h(uatB.z), u2h(uatB.w)};

        float denA = 0.f, denB = 0.f;
        half2v accA[4], accB[4];
        #pragma unroll
        for (int i = 0; i < 4; ++i) {
            accA[i] = (half2v){(_Float16)0.f, (_Float16)0.f};
            accB[i] = (half2v){(_Float16)0.f, (_Float16)0.f};
        }

        edge4(gA0, okA0, fdvA, atvA, denA, accA);
        edge4(gB0, okB0, fdvB, atvB, denB, accB);
        if (mA > 4) edge4(gA1, okA1, fdvA, atvA, denA, accA);
        if (mB > 4) edge4(gB1, okB1, fdvB, atvB, denB, accB);

        if (mA > 8) {                        // P ~ 2%
            for (int p = 8; p < mA; p += 4) {
                const int ei = p + quarter;
                const bool ok = ei < mA;
                const int eic = ei < 31 ? ei : 31;
                int s = (eic < 15) ? rec[(size_t)rdA * 16 + 1 + eic]
                                   : ovf[(size_t)(eic - 15) * L + rdA];
                s = ok ? s : 0;
                const uint4 g = *(const uint4*)&fsuA[(size_t)s * 64 + fo];
                edge4(g, ok, fdvA, atvA, denA, accA);
            }
        }
        if (mB > 8) {
            for (int p = 8; p < mB; p += 4) {
                const int ei = p + quarter;
                const bool ok = ei < mB;
                const int eic = ei < 31 ? ei : 31;
                int s = (eic < 15) ? rec[(size_t)rdB * 16 + 1 + eic]
                                   : ovf[(size_t)(eic - 15) * L + rdB];
                s = ok ? s : 0;
                const uint4 g = *(const uint4*)&fsuB[(size_t)s * 64 + fo];
                edge4(g, ok, fdvB, atvB, denB, accB);
            }
        }

        if (mA) {
            denA += __shfl_xor(denA, 16);
            denA += __shfl_xor(denA, 32);
            const half2v ih = pk2h(__builtin_amdgcn_rcpf(denA));   // denA > 0
            #pragma unroll
            for (int i = 0; i < 4; ++i) val[i] += accA[i] * ih;
        }
        if (mB) {
            denB += __shfl_xor(denB, 16);
            denB += __shfl_xor(denB, 32);
            const half2v ih = pk2h(__builtin_amdgcn_rcpf(denB));   // denB > 0
            #pragma unroll
            for (int i = 0; i < 4; ++i) val[i] += accB[i] * ih;
        }
    }

    // combine quarters' numerator contributions (packed)
    #pragma unroll
    for (int i = 0; i < 4; ++i) {
        val[i] = shfladd_h(val[i], 16);
        val[i] = shfladd_h(val[i], 32);
    }
}

// =====================================================================
// agg_gemm_pipe: persistent work-queue. Item stream per tile g:
// items 5g..5g+3 = aggregate 4 nodes each (nodes 16g+4*sub+wave);
// item 5g+4 = gemm tile g (16 rows x 4 relations), spins on tflag[g]==4.
// =====================================================================
__global__ __launch_bounds__(256) void agg_gemm_pipe(
    const int* __restrict__ rec, const int* __restrict__ ovf,
    const unsigned* __restrict__ fs_in, const unsigned* __restrict__ fd_in,
    const unsigned* __restrict__ att_h,
    unsigned* __restrict__ hb,                  // [n][64] u32 intermediate
    const unsigned short* __restrict__ Wp,      // next-layer packed section
    const float* __restrict__ bs_nx, const float* __restrict__ bd_nx,
    unsigned short* __restrict__ fs_out, unsigned short* __restrict__ fd_out,
    int* __restrict__ wq, int* __restrict__ tflag, int n)
{
    __shared__ char lsA[4096];
    __shared__ char lsC[8192];
    __shared__ int s_item;

    const int tid = threadIdx.x;
    const int nT = (n + 15) >> 4;                // tiles (n=50000 -> 3125, exact)
    const int TOTAL = nT * 5;

    for (;;) {
        if (tid == 0) s_item = atomicAdd(wq, 1);
        __syncthreads();
        const int item = s_item;
        if (item >= TOTAL) return;
        const int g = item / 5, sub = item % 5;

        if (sub < 4) {
            // ---------- producer: aggregate 4 nodes ----------
            const int wave = tid >> 6, lane = tid & 63;
            const int quarter = lane >> 4;
            const int q = lane & 15;
            const int fo = 4 * q;
            const int node = g * 16 + sub * 4 + wave;
            if (node < n) {
                half2v val[4];
                agg_node(node, n, quarter, fo, rec, ovf, fs_in, fd_in, att_h, val);
                if (lane < 16) {
                    uint4 o;
                    o.x = h2u(val[0]); o.y = h2u(val[1]);
                    o.z = h2u(val[2]); o.w = h2u(val[3]);
                    *(uint4*)&hb[(size_t)node * 64 + fo] = o;
                }
            }
            __threadfence();
            __syncthreads();
            if (tid == 0)
                __hip_atomic_fetch_add(&tflag[g], 1, __ATOMIC_RELEASE,
                                       __HIP_MEMORY_SCOPE_AGENT);
        } else {
            // ---------- consumer: gemm tile g ----------
            if (tid == 0) {
                while (__hip_atomic_load(&tflag[g], __ATOMIC_ACQUIRE,
                                         __HIP_MEMORY_SCOPE_AGENT) < 4)
                    __builtin_amdgcn_s_sleep(2);
            }
            __syncthreads();
            __threadfence();                      // invalidate L1 before hb reads

            const int row0 = g * 16;
            const int wave = tid >> 6, lane = tid & 63;
            const int half = wave & 1;
            const int mat  = wave >> 1;
            const int lo = lane & 15, quad = lane >> 4;
            const int srow = tid >> 4, schunk = tid & 15;

            {
                const unsigned short* hbs = (const unsigned short*)hb;
                const uint4 gg = *(const uint4*)&hbs[(size_t)row0 * FF + tid * 8];
                *(uint4*)&lsA[swz16(srow, schunk)] = gg;
            }
            __syncthreads();

            f16x8 A[4];
            #pragma unroll
            for (int ks = 0; ks < 4; ++ks)
                A[ks] = *(const f16x8*)&lsA[swz16(lo, ks * 4 + quad)];

            const float* bp = mat ? bd_nx : bs_nx;

            for (int r = 0; r < 4; ++r) {
                const unsigned short* Wr = Wp + (size_t)r * 2 * FF * FF;

                f16x8 B[4][4];
                #pragma unroll
                for (int nbi = 0; nbi < 4; ++nbi)
                    #pragma unroll
                    for (int ks = 0; ks < 4; ++ks) {
                        const int nb = half * 4 + nbi;
                        B[nbi][ks] = *(const f16x8*)
                            &Wr[(((((size_t)mat * 8 + nb) * 4 + ks) * 64 + lane) * 8)];
                    }

                f4v c[4];
                #pragma unroll
                for (int nbi = 0; nbi < 4; ++nbi) {
                    const float bias = bp[r * FF + (half * 4 + nbi) * 16 + lo];
                    c[nbi] = (f4v){bias, bias, bias, bias};
                }

                #pragma unroll
                for (int ks = 0; ks < 4; ++ks)
                    #pragma unroll
                    for (int nbi = 0; nbi < 4; ++nbi)
                        c[nbi] = __builtin_amdgcn_mfma_f32_16x16x32_f16(
                            A[ks], B[nbi][ks], c[nbi], 0, 0, 0);

                #pragma unroll
                for (int nbi = 0; nbi < 4; ++nbi)
                    #pragma unroll
                    for (int i = 0; i < 4; ++i) {
                        const int row = quad * 4 + i;
                        const int cb  = ((half * 4 + nbi) * 16 + lo) * 2;
                        *(unsigned short*)&lsC[mat * 4096 + swz16(row, cb >> 4) + (cb & 15)]
                            = f2h(c[nbi][i]);
                    }
                __syncthreads();

                #pragma unroll
                for (int p = 0; p < 2; ++p) {
                    const int unit = p * 256 + tid;
                    const int m    = unit >> 8;
                    const int row  = (unit >> 4) & 15;
                    const int ch   = unit & 15;
                    if (row0 + row < n) {
                        const uint4 d = *(const uint4*)&lsC[m * 4096 + swz16(row, ch)];
                        unsigned short* out = (m ? fd_out : fs_out) + (size_t)r * n * FF;
                        *(uint4*)&out[(size_t)(row0 + row) * FF + ch * 8] = d;
                    }
                }
                __syncthreads();
            }
        }
        __syncthreads();                          // protect s_item + lsA reuse
    }
}

// =====================================================================
// Final-layer aggregate (R19 body; out_f32 path).
// =====================================================================
__global__ __launch_bounds__(256) void aggregate(
    const int* __restrict__ rec, const int* __restrict__ ovf,
    const unsigned* __restrict__ fs_all, const unsigned* __restrict__ fd_all,
    const unsigned* __restrict__ att_h,
    float* __restrict__ out_f32, int n)
{
    const int node = blockIdx.x * 4 + (threadIdx.x >> 6);
    if (node >= n) return;
    const int lane = threadIdx.x & 63;
    const int quarter = lane >> 4;
    const int q = lane & 15;
    const int fo = 4 * q;

    half2v val[4];
    agg_node(node, n, quarter, fo, rec, ovf, fs_all, fd_all, att_h, val);

    // mean over heads: lane q holds feats 8q..8q+7, head = q>>2
    #pragma unroll
    for (int i = 0; i < 4; ++i) {
        val[i] = shfladd_h(val[i], 4);
        val[i] = shfladd_h(val[i], 8);
    }
    if (lane < 4) {
        float* o = &out_f32[(size_t)node * 32 + 8 * lane];
        *(float4*)&o[0] = make_float4(0.25f * (float)val[0].x, 0.25f * (float)val[0].y,
                                      0.25f * (float)val[1].x, 0.25f * (float)val[1].y);
        *(float4*)&o[4] = make_float4(0.25f * (float)val[2].x, 0.25f * (float)val[2].y,
                                      0.25f * (float)val[3].x, 0.25f * (float)val[3].y);
    }
}

// =====================================================================
extern "C" void kernel_launch(void* const* d_in, const int* in_sizes, int n_in,
                              void* d_out, int out_size, void* d_ws, size_t ws_size,
                              hipStream_t stream)
{
    const int n  = in_sizes[0] / FF;     // 50000
    const int R  = 4;
    const int ne = in_sizes[1] / R;      // 200000
    const int totalE = R * ne;
    const int L  = R * n;
    const int nrb = (n + 15) / 16;
    const int nT  = (n + 15) / 16;       // 3125 tiles

    const float* x    = (const float*)d_in[0];
    const int*   esrc = (const int*)d_in[1];
    const int*   edst = (const int*)d_in[2];

    // ---- workspace layout (~257 MB) ----
    char* p = (char*)d_ws;
    auto carve = [&p](size_t bytes) { char* q = p; p += (bytes + 255) & ~(size_t)255; return q; };
    unsigned short* fsA = (unsigned short*)carve((size_t)R * n * FF * 2);
    unsigned short* fdA = (unsigned short*)carve((size_t)R * n * FF * 2);
    unsigned short* fsB = (unsigned short*)carve((size_t)R * n * FF * 2);
    unsigned short* fdB = (unsigned short*)carve((size_t)R * n * FF * 2);
    unsigned*       hb  = (unsigned*)      carve((size_t)n * 64 * 4);
    unsigned short* Wp  = (unsigned short*)carve((size_t)3 * R * 2 * FF * FF * 2);
    unsigned*       attH= (unsigned*)      carve((size_t)3 * R * 64 * 4);
    int*            rec = (int*)           carve((size_t)L * 16 * 4);   // 64B records
    int*            ovf = (int*)           carve((size_t)17 * L * 4);   // idx 15..31
    int*            sync= (int*)           carve((size_t)(2 + 2 * nT) * 4);

    (void)hipMemsetAsync(rec, 0, (size_t)L * 16 * sizeof(int), stream);
    (void)hipMemsetAsync(sync, 0, (size_t)(2 + 2 * nT) * sizeof(int), stream);

    // ---- pack W0 + att ----
    pack0<<<515, 256, 0, stream>>>(
        (const float*)d_in[3], (const float*)d_in[5], Wp,
        (const float*)d_in[7], (const float*)d_in[12], (const float*)d_in[17],
        attH);

    // ---- fused: csr fill + gemm0 -> (fsA, fdA) + pack W1/W2 ----
    const int CB = (totalE + 1023) / 1024;
    fused2<<<CB + G0F + 1024, 256, 0, stream>>>(
        esrc, edst, rec, ovf, totalE, ne, n, CB,
        x, Wp,
        (const float*)d_in[4], (const float*)d_in[6],
        fsA, fdA, nrb,
        (const float*)d_in[8],  (const float*)d_in[10],
        (const float*)d_in[13], (const float*)d_in[15],
        Wp);

    const size_t sect = (size_t)R * 2 * FF * FF;

    // ---- pipe 1: aggregate(l0, fsA/fdA) || gemm(l1) -> fsB/fdB ----
    agg_gemm_pipe<<<PB, 256, 0, stream>>>(
        rec, ovf, (const unsigned*)fsA, (const unsigned*)fdA,
        attH + 0 * R * 64, hb,
        Wp + 1 * sect, (const float*)d_in[9], (const float*)d_in[11],
        fsB, fdB,
        sync + 0, sync + 2, n);

    // ---- pipe 2: aggregate(l1, fsB/fdB) || gemm(l2) -> fsA/fdA ----
    agg_gemm_pipe<<<PB, 256, 0, stream>>>(
        rec, ovf, (const unsigned*)fsB, (const unsigned*)fdB,
        attH + 1 * R * 64, hb,
        Wp + 2 * sect, (const float*)d_in[14], (const float*)d_in[16],
        fsA, fdA,
        sync + 1, sync + 2 + nT, n);

    // ---- layer 2 aggregate -> output ----
    aggregate<<<(n + 3) / 4, 256, 0, stream>>>(
        rec, ovf, (const unsigned*)fsA, (const unsigned*)fdA,
        attH + 2 * R * 64,
        (float*)d_out, n);
}

// Round 13
// 376.190 us; speedup vs baseline: 12.0883x; 12.0883x over previous
//
#include <hip/hip_runtime.h>
#include <math.h>

#define FF 128     // feature width (all layers)
#define G0F 1024   // gemm0 blocks inside fused2 (4/CU tail)
#define GG 2048    // mfma_gemm grid

typedef _Float16 half2v __attribute__((ext_vector_type(2)));
typedef _Float16 f16x8  __attribute__((ext_vector_type(8)));
typedef __fp16   fp16x2 __attribute__((ext_vector_type(2)));
typedef __attribute__((ext_vector_type(4))) float f4v;

__device__ __forceinline__ half2v u2h(unsigned u) {
    union { unsigned u; half2v h; } c; c.u = u; return c.h;
}
__device__ __forceinline__ unsigned h2u(half2v h) {
    union { unsigned u; half2v h; } c; c.h = h; return c.u;
}
__device__ __forceinline__ unsigned short f2h(float f) {
    _Float16 h = (_Float16)f;
    unsigned short u; __builtin_memcpy(&u, &h, 2); return u;
}
__device__ __forceinline__ half2v pk2h(float e) {
    union { fp16x2 p; half2v h; } c;
    c.p = __builtin_amdgcn_cvt_pkrtz(e, e);
    return c.h;
}
__device__ __forceinline__ float dot2(half2v a, half2v b, float c) {
#if __has_builtin(__builtin_amdgcn_fdot2)
    union { half2v h; fp16x2 p; } ca, cb;
    ca.h = a; cb.h = b;
    return __builtin_amdgcn_fdot2(ca.p, cb.p, c, false);
#else
    return c + (float)a.x * (float)b.x + (float)a.y * (float)b.y;
#endif
}
__device__ __forceinline__ half2v shfladd_h(half2v v, int mask) {
    return v + u2h(__shfl_xor(h2u(v), mask));
}
// 16B-chunk XOR swizzle inside a [16 rows][256B] LDS tile.
__device__ __forceinline__ int swz16(int row, int chunk) {
    return row * 256 + (((chunk ^ row) & 15) << 4);
}

// =====================================================================
// R26 = R19/R24 REVERT (best measured config: 373.8-378.2us).
// Ledger: aggregate levers R20 (ILP), R22 (TLP), R23 (fusion), R25
// (persistent queue) all regressed with understood mechanisms; its
// FETCH = compulsory set, L3 absorbs re-reads, ~4TB/s random-gather =
// fabric capability. CSR layouts R18/R19/R21 equivalent. This
// configuration is the measured plateau.
// =====================================================================

// ---------------- pack0: pack W0 + att (tiny pre-kernel) -------------
__global__ __launch_bounds__(256) void pack0(
    const float* __restrict__ W0s_, const float* __restrict__ W0d_,
    unsigned short* __restrict__ Wp,
    const float* __restrict__ a0, const float* __restrict__ a1,
    const float* __restrict__ a2, unsigned* __restrict__ attH)
{
    int b = blockIdx.x;
    const int tid = threadIdx.x;
    if (b < 512) {                       // 4r x 2mat x 128 x 128 = 131072
        const int t = b * 256 + tid;
        const int r   = t >> 15;
        const int mat = (t >> 14) & 1;
        const int idx = t & 16383;
        const int k = idx >> 7, nn = idx & 127;
        const float* W = mat ? W0d_ : W0s_;
        const float v = W[((size_t)r * FF + k) * FF + nn];
        const int nb = nn >> 4, lo = nn & 15;
        const int ks = k >> 5, quad = (k >> 3) & 3, j = k & 7;
        const int lane = quad * 16 + lo;
        const size_t o = ((((((size_t)r * 2 + mat) * 8 + nb) * 4 + ks) * 64 + lane) * 8) + j;
        Wp[o] = f2h(v);
        return;
    }
    b -= 512;
    const int t = b * 256 + tid;
    if (t >= 768) return;
    const int l = t >> 8, rest = t & 255;
    const float* a = (l == 0) ? a0 : (l == 1) ? a1 : a2;
    const float2 v = ((const float2*)a)[rest];
    half2v h = {(_Float16)v.x, (_Float16)v.y};
    attH[t] = h2u(h);
}

// ------- fused2: csr fill (record) + gemm0 + pack W1/W2 --------------
__global__ __launch_bounds__(256, 4) void fused2(
    const int* __restrict__ esrc_all, const int* __restrict__ edst_all,
    int* __restrict__ rec, int* __restrict__ ovf,
    int totalE, int ne, int n, int CB,
    const float* __restrict__ x,
    const unsigned short* __restrict__ Wp,
    const float* __restrict__ bs0, const float* __restrict__ bd0,
    unsigned short* __restrict__ fs_all, unsigned short* __restrict__ fd_all,
    int nrb,
    const float* __restrict__ W1s_, const float* __restrict__ W1d_,
    const float* __restrict__ W2s_, const float* __restrict__ W2d_,
    unsigned short* __restrict__ Wp_full)
{
    __shared__ char lsA[4096];
    __shared__ char lsC[8192];

    int b = blockIdx.x;
    const int tid = threadIdx.x;
    const int L = n << 2;

    if (b < CB) {
        const int t0 = b * 1024 + tid;
        #pragma unroll
        for (int k = 0; k < 4; ++k) {
            const int i = t0 + k * 256;
            if (i < totalE) {
                const int r = i / ne;
                const int rd = r * n + edst_all[i];
                const int src = esrc_all[i];
                const int idx = atomicAdd(&rec[(size_t)rd * 16], 1);
                if (idx < 15)      rec[(size_t)rd * 16 + 1 + idx] = src;
                else if (idx < 32) ovf[(size_t)(idx - 15) * L + rd] = src;
            }
        }
        return;
    }
    b -= CB;

    if (b < G0F) {
        const int wave = tid >> 6, lane = tid & 63;
        const int r = b & 3;
        const int half = wave & 1;
        const int mat  = wave >> 1;
        const int lo = lane & 15, quad = lane >> 4;

        const unsigned short* Wr = Wp + (size_t)r * 2 * FF * FF;
        const float* bp = mat ? bd0 : bs0;
        unsigned short* fs = fs_all + (size_t)r * n * FF;
        unsigned short* fd = fd_all + (size_t)r * n * FF;

        f16x8 B[4][4];
        #pragma unroll
        for (int nbi = 0; nbi < 4; ++nbi)
            #pragma unroll
            for (int ks = 0; ks < 4; ++ks) {
                const int nb = half * 4 + nbi;
                B[nbi][ks] = *(const f16x8*)
                    &Wr[(((((size_t)mat * 8 + nb) * 4 + ks) * 64 + lane) * 8)];
            }

        float bias[4];
        #pragma unroll
        for (int nbi = 0; nbi < 4; ++nbi)
            bias[nbi] = bp[r * FF + (half * 4 + nbi) * 16 + lo];

        const int srow = tid >> 4, schunk = tid & 15;
        const int stride = G0F >> 2;
        for (int rb = b >> 2; rb < nrb; rb += stride) {
            const int row0 = rb * 16;
            {
                const float* xs = &x[(size_t)row0 * FF + tid * 8];
                const float4 p0 = *(const float4*)&xs[0];
                const float4 p1 = *(const float4*)&xs[4];
                f16x8 v;
                v[0] = (_Float16)p0.x; v[1] = (_Float16)p0.y;
                v[2] = (_Float16)p0.z; v[3] = (_Float16)p0.w;
                v[4] = (_Float16)p1.x; v[5] = (_Float16)p1.y;
                v[6] = (_Float16)p1.z; v[7] = (_Float16)p1.w;
                *(f16x8*)&lsA[swz16(srow, schunk)] = v;
            }
            __syncthreads();

            f16x8 A[4];
            #pragma unroll
            for (int ks = 0; ks < 4; ++ks)
                A[ks] = *(const f16x8*)&lsA[swz16(lo, ks * 4 + quad)];

            f4v c[4];
            #pragma unroll
            for (int nbi = 0; nbi < 4; ++nbi)
                c[nbi] = (f4v){bias[nbi], bias[nbi], bias[nbi], bias[nbi]};

            #pragma unroll
            for (int ks = 0; ks < 4; ++ks)
                #pragma unroll
                for (int nbi = 0; nbi < 4; ++nbi)
                    c[nbi] = __builtin_amdgcn_mfma_f32_16x16x32_f16(
                        A[ks], B[nbi][ks], c[nbi], 0, 0, 0);

            #pragma unroll
            for (int nbi = 0; nbi < 4; ++nbi)
                #pragma unroll
                for (int i = 0; i < 4; ++i) {
                    const int row = quad * 4 + i;
                    const int cb  = ((half * 4 + nbi) * 16 + lo) * 2;
                    *(unsigned short*)&lsC[mat * 4096 + swz16(row, cb >> 4) + (cb & 15)]
                        = f2h(c[nbi][i]);
                }
            __syncthreads();

            #pragma unroll
            for (int p = 0; p < 2; ++p) {
                const int unit = p * 256 + tid;
                const int m    = unit >> 8;
                const int row  = (unit >> 4) & 15;
                const int ch   = unit & 15;
                const uint4 d = *(const uint4*)&lsC[m * 4096 + swz16(row, ch)];
                unsigned short* out = m ? fd : fs;
                *(uint4*)&out[(size_t)(row0 + row) * FF + ch * 8] = d;
            }
            __syncthreads();
        }
        return;
    }
    b -= G0F;

    const int t = b * 256 + tid;
    if (t >= 2 * 4 * 2 * FF * FF) return;
    const int l    = 1 + (t >> 17);
    const int rest = t & 131071;
    const int r    = rest >> 15;
    const int mat  = (rest >> 14) & 1;
    const int idx  = rest & 16383;
    const int k = idx >> 7, nn = idx & 127;
    const float* W = (l == 1) ? (mat ? W1d_ : W1s_)
                              : (mat ? W2d_ : W2s_);
    const float v = W[((size_t)r * FF + k) * FF + nn];
    const int nb = nn >> 4, lo = nn & 15;
    const int ks = k >> 5, quad = (k >> 3) & 3, j = k & 7;
    const int lane = quad * 16 + lo;
    const size_t o = (((((((size_t)l * 4 + r) * 2 + mat) * 8 + nb) * 4 + ks) * 64 + lane) * 8) + j;
    Wp_full[o] = f2h(v);
}

// =====================================================================
// Batched MFMA GEMM over all 4 relations, f16 inputs (layers 1,2).
// =====================================================================
__global__ __launch_bounds__(256, 4) void mfma_gemm(
    const unsigned short* __restrict__ hb,
    const unsigned short* __restrict__ Wp,
    const float* __restrict__ bs_all,
    const float* __restrict__ bd_all,
    unsigned short* __restrict__ fs_all,
    unsigned short* __restrict__ fd_all,
    int nrb, int n)
{
    __shared__ char lsA[4096];
    __shared__ char lsC[8192];

    const int tid = threadIdx.x;
    const int wave = tid >> 6, lane = tid & 63;
    const int r = blockIdx.x & 3;
    const int half = wave & 1;
    const int mat  = wave >> 1;
    const int lo = lane & 15, quad = lane >> 4;

    const unsigned short* Wr = Wp + (size_t)r * 2 * FF * FF;
    const float* bp = mat ? bd_all : bs_all;
    unsigned short* fs = fs_all + (size_t)r * n * FF;
    unsigned short* fd = fd_all + (size_t)r * n * FF;

    f16x8 B[4][4];
    #pragma unroll
    for (int nbi = 0; nbi < 4; ++nbi)
        #pragma unroll
        for (int ks = 0; ks < 4; ++ks) {
            const int nb = half * 4 + nbi;
            B[nbi][ks] = *(const f16x8*)
                &Wr[(((((size_t)mat * 8 + nb) * 4 + ks) * 64 + lane) * 8)];
        }

    float bias[4];
    #pragma unroll
    for (int nbi = 0; nbi < 4; ++nbi)
        bias[nbi] = bp[r * FF + (half * 4 + nbi) * 16 + lo];

    const int srow = tid >> 4, schunk = tid & 15;
    const int stride = gridDim.x >> 2;
    for (int rb = blockIdx.x >> 2; rb < nrb; rb += stride) {
        const int row0 = rb * 16;
        {
            const uint4 g = *(const uint4*)&hb[(size_t)row0 * FF + tid * 8];
            *(uint4*)&lsA[swz16(srow, schunk)] = g;
        }
        __syncthreads();

        f16x8 A[4];
        #pragma unroll
        for (int ks = 0; ks < 4; ++ks)
            A[ks] = *(const f16x8*)&lsA[swz16(lo, ks * 4 + quad)];

        f4v c[4];
        #pragma unroll
        for (int nbi = 0; nbi < 4; ++nbi)
            c[nbi] = (f4v){bias[nbi], bias[nbi], bias[nbi], bias[nbi]};

        #pragma unroll
        for (int ks = 0; ks < 4; ++ks)
            #pragma unroll
            for (int nbi = 0; nbi < 4; ++nbi)
                c[nbi] = __builtin_amdgcn_mfma_f32_16x16x32_f16(
                    A[ks], B[nbi][ks], c[nbi], 0, 0, 0);

        #pragma unroll
        for (int nbi = 0; nbi < 4; ++nbi)
            #pragma unroll
            for (int i = 0; i < 4; ++i) {
                const int row = quad * 4 + i;
                const int cb  = ((half * 4 + nbi) * 16 + lo) * 2;
                *(unsigned short*)&lsC[mat * 4096 + swz16(row, cb >> 4) + (cb & 15)]
                    = f2h(c[nbi][i]);
            }
        __syncthreads();

        #pragma unroll
        for (int p = 0; p < 2; ++p) {
            const int unit = p * 256 + tid;
            const int m    = unit >> 8;
            const int row  = (unit >> 4) & 15;
            const int ch   = unit & 15;
            const uint4 d = *(const uint4*)&lsC[m * 4096 + swz16(row, ch)];
            unsigned short* out = m ? fd : fs;
            *(uint4*)&out[(size_t)(row0 + row) * FF + ch * 8] = d;
        }
        __syncthreads();
    }
}

// =====================================================================
// Fused aggregate (R19: record layout, pair structure).
// =====================================================================
__device__ __forceinline__ void edge4(
    uint4 g, bool ok, const half2v* fdv, const half2v* atv,
    float& den, half2v* acc)
{
    const half2v C02 = {(_Float16)0.2f, (_Float16)0.2f};
    half2v f[4] = {u2h(g.x), u2h(g.y), u2h(g.z), u2h(g.w)};
    float v = 0.f;
    #pragma unroll
    for (int i = 0; i < 4; ++i) {
        const half2v z = f[i] + fdv[i];
        const half2v l = __builtin_elementwise_max(z, z * C02);
        v = dot2(l, atv[i], v);
    }
    v += __shfl_xor(v, 2);
    v += __shfl_xor(v, 1);
    const float e = ok ? __expf(v) : 0.f;
    den += e;
    const half2v eh = pk2h(e);
    #pragma unroll
    for (int i = 0; i < 4; ++i) acc[i] += eh * f[i];
}

__global__ __launch_bounds__(256) void aggregate(
    const int* __restrict__ rec,             // [R*n][16] {cnt, s0..s14}
    const int* __restrict__ ovf,             // [17][R*n] planes, idx 15..31
    const unsigned* __restrict__ fs_all,     // [R][n][64] f16 pairs
    const unsigned* __restrict__ fd_all,
    const unsigned* __restrict__ att_h,      // this layer: [R][64] f16 pairs
    unsigned* __restrict__ out_h,            // [n][64] or null
    float* __restrict__ out_f32,             // [n][32] or null
    int n)
{
    const int node = blockIdx.x * 4 + (threadIdx.x >> 6);
    if (node >= n) return;
    const int lane = threadIdx.x & 63;
    const int quarter = lane >> 4;
    const int q = lane & 15;
    const int fo = 4 * q;
    const int L = n << 2;

    int m[4], i0[4], i1[4];
    #pragma unroll
    for (int r = 0; r < 4; ++r) {
        const int rd = r * n + node;
        const int* rp = &rec[(size_t)rd * 16];
        m[r]  = rp[0];
        i0[r] = rp[1 + quarter];
        i1[r] = rp[5 + quarter];
    }

    half2v val[4];
    #pragma unroll
    for (int i = 0; i < 4; ++i) val[i] = (half2v){(_Float16)0.f, (_Float16)0.f};

    #pragma unroll
    for (int rp2 = 0; rp2 < 2; ++rp2) {
        const int ra = 2 * rp2, rb = 2 * rp2 + 1;
        const int rdA = ra * n + node;
        const int rdB = rb * n + node;
        const int mA = m[ra], mB = m[rb];
        const unsigned* fsuA = fs_all + (size_t)ra * n * 64;
        const unsigned* fsuB = fs_all + (size_t)rb * n * 64;

        const uint4 ufdA = *(const uint4*)&fd_all[(size_t)rdA * 64 + fo];
        const uint4 ufdB = *(const uint4*)&fd_all[(size_t)rdB * 64 + fo];
        const uint4 uatA = *(const uint4*)&att_h[ra * 64 + fo];
        const uint4 uatB = *(const uint4*)&att_h[rb * 64 + fo];

        const bool okA0 = quarter < mA, okA1 = 4 + quarter < mA;
        const bool okB0 = quarter < mB, okB1 = 4 + quarter < mB;
        int iA0 = okA0 ? i0[ra] : 0;
        int iB0 = okB0 ? i0[rb] : 0;
        int iA1 = okA1 ? i1[ra] : 0;
        int iB1 = okB1 ? i1[rb] : 0;
        const uint4 gA0 = *(const uint4*)&fsuA[(size_t)iA0 * 64 + fo];
        const uint4 gB0 = *(const uint4*)&fsuB[(size_t)iB0 * 64 + fo];
        const uint4 gA1 = *(const uint4*)&fsuA[(size_t)iA1 * 64 + fo];
        const uint4 gB1 = *(const uint4*)&fsuB[(size_t)iB1 * 64 + fo];

        half2v fdvA[4] = {u2h(ufdA.x), u2h(ufdA.y), u2h(ufdA.z), u2h(ufdA.w)};
        half2v atvA[4] = {u2h(uatA.x), u2h(uatA.y), u2h(uatA.z), u2h(uatA.w)};
        half2v fdvB[4] = {u2h(ufdB.x), u2h(ufdB.y), u2h(ufdB.z), u2h(ufdB.w)};
        half2v atvB[4] = {u2h(uatB.x), u2h(uatB.y), u2h(uatB.z), u2h(uatB.w)};

        float denA = 0.f, denB = 0.f;
        half2v accA[4], accB[4];
        #pragma unroll
        for (int i = 0; i < 4; ++i) {
            accA[i] = (half2v){(_Float16)0.f, (_Float16)0.f};
            accB[i] = (half2v){(_Float16)0.f, (_Float16)0.f};
        }

        edge4(gA0, okA0, fdvA, atvA, denA, accA);
        edge4(gB0, okB0, fdvB, atvB, denB, accB);
        if (mA > 4) edge4(gA1, okA1, fdvA, atvA, denA, accA);
        if (mB > 4) edge4(gB1, okB1, fdvB, atvB, denB, accB);

        if (mA > 8) {                        // P ~ 2%
            for (int p = 8; p < mA; p += 4) {
                const int ei = p + quarter;
                const bool ok = ei < mA;
                const int eic = ei < 31 ? ei : 31;
                int s = (eic < 15) ? rec[(size_t)rdA * 16 + 1 + eic]
                                   : ovf[(size_t)(eic - 15) * L + rdA];
                s = ok ? s : 0;
                const uint4 g = *(const uint4*)&fsuA[(size_t)s * 64 + fo];
                edge4(g, ok, fdvA, atvA, denA, accA);
            }
        }
        if (mB > 8) {
            for (int p = 8; p < mB; p += 4) {
                const int ei = p + quarter;
                const bool ok = ei < mB;
                const int eic = ei < 31 ? ei : 31;
                int s = (eic < 15) ? rec[(size_t)rdB * 16 + 1 + eic]
                                   : ovf[(size_t)(eic - 15) * L + rdB];
                s = ok ? s : 0;
                const uint4 g = *(const uint4*)&fsuB[(size_t)s * 64 + fo];
                edge4(g, ok, fdvB, atvB, denB, accB);
            }
        }

        if (mA) {
            denA += __shfl_xor(denA, 16);
            denA += __shfl_xor(denA, 32);
            const half2v ih = pk2h(__builtin_amdgcn_rcpf(denA));   // denA > 0
            #pragma unroll
            for (int i = 0; i < 4; ++i) val[i] += accA[i] * ih;
        }
        if (mB) {
            denB += __shfl_xor(denB, 16);
            denB += __shfl_xor(denB, 32);
            const half2v ih = pk2h(__builtin_amdgcn_rcpf(denB));   // denB > 0
            #pragma unroll
            for (int i = 0; i < 4; ++i) val[i] += accB[i] * ih;
        }
    }

    #pragma unroll
    for (int i = 0; i < 4; ++i) {
        val[i] = shfladd_h(val[i], 16);
        val[i] = shfladd_h(val[i], 32);
    }

    if (out_f32) {
        #pragma unroll
        for (int i = 0; i < 4; ++i) {
            val[i] = shfladd_h(val[i], 4);
            val[i] = shfladd_h(val[i], 8);
        }
        if (lane < 4) {
            float* o = &out_f32[(size_t)node * 32 + 8 * lane];
            *(float4*)&o[0] = make_float4(0.25f * (float)val[0].x, 0.25f * (float)val[0].y,
                                          0.25f * (float)val[1].x, 0.25f * (float)val[1].y);
            *(float4*)&o[4] = make_float4(0.25f * (float)val[2].x, 0.25f * (float)val[2].y,
                                          0.25f * (float)val[3].x, 0.25f * (float)val[3].y);
        }
    } else {
        if (lane < 16) {
            uint4 o;
            o.x = h2u(val[0]); o.y = h2u(val[1]);
            o.z = h2u(val[2]); o.w = h2u(val[3]);
            *(uint4*)&out_h[(size_t)node * 64 + fo] = o;
        }
    }
}

// =====================================================================
extern "C" void kernel_launch(void* const* d_in, const int* in_sizes, int n_in,
                              void* d_out, int out_size, void* d_ws, size_t ws_size,
                              hipStream_t stream)
{
    const int n  = in_sizes[0] / FF;     // 50000
    const int R  = 4;
    const int ne = in_sizes[1] / R;      // 200000
    const int totalE = R * ne;
    const int L  = R * n;
    const int nrb = (n + 15) / 16;

    const float* x    = (const float*)d_in[0];
    const int*   esrc = (const int*)d_in[1];
    const int*   edst = (const int*)d_in[2];

    char* p = (char*)d_ws;
    auto carve = [&p](size_t bytes) { char* q = p; p += (bytes + 255) & ~(size_t)255; return q; };
    unsigned*       hbA    = (unsigned*)      carve((size_t)n * 64 * 4);
    unsigned*       hbB    = (unsigned*)      carve((size_t)n * 64 * 4);
    unsigned short* fs_all = (unsigned short*)carve((size_t)R * n * FF * 2);
    unsigned short* fd_all = (unsigned short*)carve((size_t)R * n * FF * 2);
    unsigned short* Wp     = (unsigned short*)carve((size_t)3 * R * 2 * FF * FF * 2);
    unsigned*       attH   = (unsigned*)      carve((size_t)3 * R * 64 * 4);
    int*            rec    = (int*)           carve((size_t)L * 16 * 4);
    int*            ovf    = (int*)           carve((size_t)17 * L * 4);

    (void)hipMemsetAsync(rec, 0, (size_t)L * 16 * sizeof(int), stream);

    pack0<<<515, 256, 0, stream>>>(
        (const float*)d_in[3], (const float*)d_in[5], Wp,
        (const float*)d_in[7], (const float*)d_in[12], (const float*)d_in[17],
        attH);

    const int CB = (totalE + 1023) / 1024;
    fused2<<<CB + G0F + 1024, 256, 0, stream>>>(
        esrc, edst, rec, ovf, totalE, ne, n, CB,
        x, Wp,
        (const float*)d_in[4], (const float*)d_in[6],
        fs_all, fd_all, nrb,
        (const float*)d_in[8],  (const float*)d_in[10],
        (const float*)d_in[13], (const float*)d_in[15],
        Wp);

    unsigned* bufs[3] = {hbA, hbB, nullptr};
    for (int l = 0; l < 3; ++l) {
        if (l > 0) {
            const float* bsrc = (const float*)d_in[3 + 5 * l + 1];
            const float* bdst = (const float*)d_in[3 + 5 * l + 3];
            mfma_gemm<<<GG, 256, 0, stream>>>(
                (const unsigned short*)bufs[l - 1],
                Wp + (size_t)l * R * 2 * FF * FF,
                bsrc, bdst, fs_all, fd_all, nrb, n);
        }
        const int last = (l == 2);
        aggregate<<<(n + 3) / 4, 256, 0, stream>>>(
            rec, ovf,
            (const unsigned*)fs_all, (const unsigned*)fd_all,
            attH + (size_t)l * R * 64,
            last ? nullptr : bufs[l],
            last ? (float*)d_out : nullptr, n);
    }
}